// Round 6
// baseline (262.935 us; speedup 1.0000x reference)
//
#include <hip/hip_runtime.h>
#include <math.h>

#define NN 100000
#define NE 1600000
#define F_IN 128
#define C 128           // N_HEADS * F_OUT
#define NEG_SLOPE 0.2f
#define PROJ_NB ((NN + 63) / 64)       // 1563

// counting-sort geometry
#define NBLK1 256                       // hist/scatter blocks
#define EPB ((NE + NBLK1 - 1) / NBLK1)  // 6250 edges per block
#define BSHIFT 9
#define NBUCK ((NN + 511) / 512)        // 196 (buckets indexed by dst>>9)

#define WCONV_NB 16
#define FAT1_NB (WCONV_NB + NBLK1)      // 272: wconv || sort1
#define FAT2_NB (NBLK1 + PROJ_NB)       // 1819: sort2 || proj

typedef __attribute__((ext_vector_type(8))) short short8;    // 8 x bf16
typedef __attribute__((ext_vector_type(4))) float f32x4;
typedef __attribute__((ext_vector_type(4))) float floatx4;
typedef __attribute__((ext_vector_type(4))) unsigned short ushortx4;

static __device__ __forceinline__ unsigned short f2bf(float f) {
    unsigned int u = __float_as_uint(f);
    unsigned int r = (u + 0x7fff + ((u >> 16) & 1)) >> 16;  // RNE
    return (unsigned short)r;
}
static __device__ __forceinline__ float bf2f(unsigned short h) {
    return __uint_as_float((unsigned int)h << 16);
}
static __device__ __forceinline__ float lrelu(float x) {
    return (x > 0.f) ? x : NEG_SLOPE * x;
}

// ---------------------------------------------------------------------------
// fat1: blocks [0,16) build Btf (fragment-major B); blocks [16,272) are the
// per-block LDS histogram of dst>>9, written TRANSPOSED: counts[bucket][blk].
// The two parts are data-independent -> they overlap on the CUs.
// ---------------------------------------------------------------------------
__global__ __launch_bounds__(256)
void fat1_kernel(const float* __restrict__ W,
                 const float* __restrict__ Wr,
                 unsigned short* __restrict__ Btf,
                 const int* __restrict__ dst,
                 int* __restrict__ counts)
{
    __shared__ int h[256];
    const int tid = threadIdx.x;

    if (blockIdx.x < WCONV_NB) {
        int g = blockIdx.x * 256 + tid;   // 0..4095
        int nt = g >> 8;
        int kc = (g >> 6) & 3;
        int l  = g & 63;
        int n  = nt * 16 + (l & 15);
        int kb = kc * 32 + (l >> 4) * 8;
        unsigned short v[8];
        #pragma unroll
        for (int j = 0; j < 8; ++j) {
            int k = kb + j;
            float f = (n < 128) ? W[(size_t)k * 128 + n]
                                : Wr[(size_t)k * 128 + (n - 128)];
            v[j] = f2bf(f);
        }
        *(short8*)&Btf[(size_t)g * 8] = *(short8*)v;
        return;
    }

    const int hb = blockIdx.x - WCONV_NB;     // 0..255
    h[tid] = 0;
    __syncthreads();
    const int e0 = hb * EPB;
    const int e1 = min(NE, e0 + EPB);
    for (int e = e0 + tid; e < e1; e += 256)
        atomicAdd(&h[dst[e] >> BSHIFT], 1);
    __syncthreads();
    counts[tid * NBLK1 + hb] = h[tid];        // transposed layout
}

// ---------------------------------------------------------------------------
// sortscan: thread t owns bucket t. Transposed counts -> contiguous int4
// streaming (parallel across 256 threads, MLP via unroll), in-place exclusive
// prefix across blocks; then cross-bucket exclusive scan -> bucket_base.
// ---------------------------------------------------------------------------
__global__ __launch_bounds__(256)
void sortscan_kernel(int* __restrict__ counts, int* __restrict__ bucket_base)
{
    __shared__ int wsum[4];
    const int t = threadIdx.x, lane = t & 63, wid = t >> 6;
    const int base = t * NBLK1;
    int run = 0;
    #pragma unroll 8
    for (int g = 0; g < NBLK1 / 4; ++g) {
        int4 c = *(const int4*)&counts[base + g * 4];
        int4 w;
        w.x = run;
        w.y = w.x + c.x;
        w.z = w.y + c.y;
        w.w = w.z + c.z;
        run = w.w + c.w;
        *(int4*)&counts[base + g * 4] = w;
    }
    int v0 = run, v = run;
    #pragma unroll
    for (int off = 1; off < 64; off <<= 1) {
        int u = __shfl_up(v, off, 64);
        if (lane >= off) v += u;
    }
    if (lane == 63) wsum[wid] = v;
    __syncthreads();
    if (t == 0) {
        int r = 0;
        #pragma unroll
        for (int s = 0; s < 4; ++s) { int tmp = wsum[s]; wsum[s] = r; r += tmp; }
    }
    __syncthreads();
    int excl = wsum[wid] + (v - v0);
    bucket_base[t] = excl;
    if (t == 255) bucket_base[256] = excl + v0;   // == NE
}

// ---------------------------------------------------------------------------
// fat2: blocks [0,256) = sort2 (bucket-major scatter via LDS cursors);
// blocks [256,1819) = projection GEMM. Independent -> proj (~40us) hides
// sort2 (~15us). Shared memory overlaid (sort2 uses 1KB of proj's 19.5KB).
// bpack = (dst&511)<<20 | src   (src < 2^17)
// ---------------------------------------------------------------------------
__global__ __launch_bounds__(256, 4)
void fat2_kernel(const int* __restrict__ src, const int* __restrict__ dst,
                 const int* __restrict__ counts,
                 const int* __restrict__ bucket_base,
                 int* __restrict__ bpack,
                 const float* __restrict__ feat,
                 const unsigned short* __restrict__ Btf,
                 const float* __restrict__ att_src,
                 const float* __restrict__ att_dst,
                 unsigned short* __restrict__ xb,
                 unsigned short* __restrict__ resb,
                 float* __restrict__ a_s,
                 float* __restrict__ a_d)
{
    __shared__ __align__(16) char smem[19456];
    const int tid = threadIdx.x;

    if (blockIdx.x < NBLK1) {                 // ---- sort2 part ----
        int* cur = (int*)smem;
        cur[tid] = bucket_base[tid] + counts[tid * NBLK1 + blockIdx.x];
        __syncthreads();
        const int e0 = blockIdx.x * EPB;
        const int e1 = min(NE, e0 + EPB);
        for (int e = e0 + tid; e < e1; e += 256) {
            int d = dst[e];
            int s = src[e];
            int pos = atomicAdd(&cur[d >> BSHIFT], 1);
            bpack[pos] = ((d & 511) << 20) | s;
        }
        return;
    }

    // ---- proj part ----
    const int pb = blockIdx.x - NBLK1;
    float* T2base = (float*)smem;                          // 4 x 16*68 floats
    float (*s_as)[4] = (float(*)[4])(smem + 17408);        // 64 x 4
    float (*s_ad)[4] = (float(*)[4])(smem + 18432);        // 64 x 4

    const int base = pb * 64;
    const int l = tid & 63;
    const int w = tid >> 6;
    const int quad = l >> 4;
    const int lo16 = l & 15;
    const int arow = w * 16 + lo16;
    const int nclamp = min(base + arow, NN - 1);   // safe row for last block

    short8 af[4];
    #pragma unroll
    for (int kc = 0; kc < 4; ++kc) {
        const float* fp = &feat[(size_t)nclamp * F_IN + kc * 32 + quad * 8];
        floatx4 f0 = __builtin_nontemporal_load((const floatx4*)fp);
        floatx4 f1 = __builtin_nontemporal_load((const floatx4*)(fp + 4));
        unsigned short v[8];
        v[0] = f2bf(f0.x); v[1] = f2bf(f0.y); v[2] = f2bf(f0.z); v[3] = f2bf(f0.w);
        v[4] = f2bf(f1.x); v[5] = f2bf(f1.y); v[6] = f2bf(f1.z); v[7] = f2bf(f1.w);
        af[kc] = *(short8*)v;
    }

    f32x4 acc[16];
    #pragma unroll
    for (int nt = 0; nt < 16; ++nt) acc[nt] = (f32x4){0.f, 0.f, 0.f, 0.f};

    #pragma unroll
    for (int nt = 0; nt < 16; ++nt) {
        const unsigned short* bp = &Btf[(size_t)(nt * 4) * 512 + l * 8];
        short8 b0 = *(const short8*)&bp[0];
        short8 b1 = *(const short8*)&bp[512];
        short8 b2 = *(const short8*)&bp[1024];
        short8 b3 = *(const short8*)&bp[1536];
        acc[nt] = __builtin_amdgcn_mfma_f32_16x16x32_bf16(af[0], b0, acc[nt], 0, 0, 0);
        acc[nt] = __builtin_amdgcn_mfma_f32_16x16x32_bf16(af[1], b1, acc[nt], 0, 0, 0);
        acc[nt] = __builtin_amdgcn_mfma_f32_16x16x32_bf16(af[2], b2, acc[nt], 0, 0, 0);
        acc[nt] = __builtin_amdgcn_mfma_f32_16x16x32_bf16(af[3], b3, acc[nt], 0, 0, 0);
    }

    float* T2 = T2base + w * (16 * 68);   // wave-private [16][68]
    const int g  = l >> 4;
    const int cf = (l & 15) * 4;

    #pragma unroll
    for (int p = 0; p < 2; ++p) {
        #pragma unroll
        for (int ntl = 0; ntl < 4; ++ntl) {
            int nt = p * 4 + ntl;
            #pragma unroll
            for (int r = 0; r < 4; ++r)
                T2[(quad * 4 + r) * 68 + ntl * 16 + lo16] = acc[nt][r];
        }
        floatx4 ws4 = *(const floatx4*)&att_src[p * 64 + cf];
        floatx4 wd4 = *(const floatx4*)&att_dst[p * 64 + cf];
        float ps[4], pd[4];
        #pragma unroll
        for (int it = 0; it < 4; ++it) {
            int row = it * 4 + g;
            floatx4 v = *(floatx4*)&T2[row * 68 + cf];
            int node = base + w * 16 + row;
            ushortx4 hh;
            hh.x = f2bf(v.x); hh.y = f2bf(v.y); hh.z = f2bf(v.z); hh.w = f2bf(v.w);
            if (node < NN)
                __builtin_nontemporal_store(hh,
                    (ushortx4*)&xb[(size_t)node * C + p * 64 + cf]);
            ps[it] = v.x * ws4.x + v.y * ws4.y + v.z * ws4.z + v.w * ws4.w;
            pd[it] = v.x * wd4.x + v.y * wd4.y + v.z * wd4.z + v.w * wd4.w;
        }
        #pragma unroll
        for (int it = 0; it < 4; ++it) {
            #pragma unroll
            for (int d = 1; d < 8; d <<= 1) {
                ps[it] += __shfl_xor(ps[it], d, 64);
                pd[it] += __shfl_xor(pd[it], d, 64);
            }
        }
        if ((l & 7) == 0) {
            int hh = p * 2 + ((l & 15) >> 3);
            #pragma unroll
            for (int it = 0; it < 4; ++it) {
                int lr = w * 16 + it * 4 + g;
                s_as[lr][hh] = ps[it];
                s_ad[lr][hh] = pd[it];
            }
        }
    }

    #pragma unroll
    for (int p = 0; p < 2; ++p) {
        #pragma unroll
        for (int ntl = 0; ntl < 4; ++ntl) {
            int nt = 8 + p * 4 + ntl;
            #pragma unroll
            for (int r = 0; r < 4; ++r)
                T2[(quad * 4 + r) * 68 + ntl * 16 + lo16] = acc[nt][r];
        }
        #pragma unroll
        for (int it = 0; it < 4; ++it) {
            int row = it * 4 + g;
            floatx4 v = *(floatx4*)&T2[row * 68 + cf];
            int node = base + w * 16 + row;
            ushortx4 hh;
            hh.x = f2bf(v.x); hh.y = f2bf(v.y); hh.z = f2bf(v.z); hh.w = f2bf(v.w);
            if (node < NN)
                __builtin_nontemporal_store(hh,
                    (ushortx4*)&resb[(size_t)node * C + p * 64 + cf]);
        }
    }

    __syncthreads();
    int idx = pb * 256 + tid;   // = base*4 + tid
    if (idx < NN * 4) {
        a_s[idx] = ((float*)s_as)[tid];
        a_d[idx] = ((float*)s_ad)[tid];
    }
}

// ---------------------------------------------------------------------------
// sort3: per-bucket (512 nodes) CSR finalize.
// ---------------------------------------------------------------------------
__global__ __launch_bounds__(512)
void sort3_kernel(const int* __restrict__ bpack,
                  const int* __restrict__ bucket_base,
                  int* __restrict__ row_ptr,
                  int* __restrict__ csr_src)
{
    __shared__ int cnt[512];
    __shared__ int cur[512];
    __shared__ int wsum[8];
    const int t = threadIdx.x, lane = t & 63, wid = t >> 6;
    const int b = blockIdx.x;
    const int ebeg = bucket_base[b];
    const int eend = bucket_base[b + 1];
    cnt[t] = 0;
    __syncthreads();
    for (int e = ebeg + t; e < eend; e += 512)
        atomicAdd(&cnt[bpack[e] >> 20], 1);
    __syncthreads();
    int v0 = cnt[t], v = v0;
    #pragma unroll
    for (int off = 1; off < 64; off <<= 1) {
        int u = __shfl_up(v, off, 64);
        if (lane >= off) v += u;
    }
    if (lane == 63) wsum[wid] = v;
    __syncthreads();
    if (t == 0) {
        int r = 0;
        #pragma unroll
        for (int s = 0; s < 8; ++s) { int tmp = wsum[s]; wsum[s] = r; r += tmp; }
    }
    __syncthreads();
    int excl = wsum[wid] + (v - v0);
    cur[t] = excl;
    int n = (b << BSHIFT) + t;
    if (n < NN) row_ptr[n] = ebeg + excl;
    if (b == NBUCK - 1 && t == 0) row_ptr[NN] = NE;
    __syncthreads();
    for (int e = ebeg + t; e < eend; e += 512) {
        int p = bpack[e];
        int pos = atomicAdd(&cur[p >> 20], 1);
        csr_src[ebeg + pos] = p & 0xFFFFF;
    }
}

// ---------------------------------------------------------------------------
// aggregation: QUARTER-WAVE per dst node (round-3 measured-best form).
// The random-256B gather is at its BW ceiling (~3.8 TB/s counted, FETCH ==
// compulsory 8-XCD traffic) -- keep the low-VGPR high-occupancy variant.
// ---------------------------------------------------------------------------
__global__ __launch_bounds__(256)
void agg_kernel(const unsigned short* __restrict__ xb,
                const unsigned short* __restrict__ resb,
                const float* __restrict__ a_s,
                const float* __restrict__ a_d,
                const int* __restrict__ row_ptr,
                const int* __restrict__ csr_src,
                float* __restrict__ out)
{
    __shared__ float s_alpha[4][4][68];   // [wave][quad][i*4+h]
    __shared__ int   s_srcs[4][4][17];
    const int tid = threadIdx.x;
    const int w   = tid >> 6;
    const int l   = tid & 63;
    const int q   = l >> 4;        // node slot within wave
    const int t16 = l & 15;        // lane within quad
    const int h   = t16 >> 2;      // head owning this lane's 8 channels

    const int n = blockIdx.x * 16 + w * 4 + q;   // < NN always (6250*16=NN)
    const int r0  = row_ptr[n];
    const int deg = row_ptr[n + 1] - r0;

    // residual row: load early (independent of gather chain)
    short8 rv = *(const short8*)&resb[(size_t)n * C + t16 * 8];
    const float4 ad4 = *(const float4*)&a_d[n * 4];

    // max degree over the 4 quads of this wave -> unified chunk loop
    int dm = deg;
    dm = max(dm, __shfl_xor(dm, 16, 64));
    dm = max(dm, __shfl_xor(dm, 32, 64));

    float acc8[8];
    #pragma unroll
    for (int j = 0; j < 8; ++j) acc8[j] = 0.f;
    float dx = 0.f, dy = 0.f, dz = 0.f, dw = 0.f;

    for (int c0 = 0; c0 < dm; c0 += 16) {
        int e = c0 + t16;
        int s = 0;
        float4 ex = {0.f, 0.f, 0.f, 0.f};
        if (e < deg) {
            s = csr_src[r0 + e];
            float4 as4 = *(const float4*)&a_s[s * 4];
            ex.x = __expf(lrelu(as4.x + ad4.x));
            ex.y = __expf(lrelu(as4.y + ad4.y));
            ex.z = __expf(lrelu(as4.z + ad4.z));
            ex.w = __expf(lrelu(as4.w + ad4.w));
            dx += ex.x; dy += ex.y; dz += ex.z; dw += ex.w;
        }
        s_srcs[w][q][t16] = s;                      // wave-private; DS in-order
        *(float4*)&s_alpha[w][q][t16 * 4] = ex;

        int cn = min(16, deg - c0);                 // <=0 for finished quads
        #pragma unroll 2
        for (int i = 0; i < cn; ++i) {
            int   si = s_srcs[w][q][i];             // LDS broadcast within quad
            float al = s_alpha[w][q][i * 4 + h];
            short8 uv = *(const short8*)&xb[(size_t)si * C + t16 * 8];
            acc8[0] = fmaf(al, bf2f((unsigned short)uv[0]), acc8[0]);
            acc8[1] = fmaf(al, bf2f((unsigned short)uv[1]), acc8[1]);
            acc8[2] = fmaf(al, bf2f((unsigned short)uv[2]), acc8[2]);
            acc8[3] = fmaf(al, bf2f((unsigned short)uv[3]), acc8[3]);
            acc8[4] = fmaf(al, bf2f((unsigned short)uv[4]), acc8[4]);
            acc8[5] = fmaf(al, bf2f((unsigned short)uv[5]), acc8[5]);
            acc8[6] = fmaf(al, bf2f((unsigned short)uv[6]), acc8[6]);
            acc8[7] = fmaf(al, bf2f((unsigned short)uv[7]), acc8[7]);
        }
    }

    // denominator: reduce within quad (xor over lane bits 0..3)
    #pragma unroll
    for (int d = 1; d < 16; d <<= 1) {
        dx += __shfl_xor(dx, d, 64);
        dy += __shfl_xor(dy, d, 64);
        dz += __shfl_xor(dz, d, 64);
        dw += __shfl_xor(dw, d, 64);
    }
    float den = (h == 0) ? dx : (h == 1) ? dy : (h == 2) ? dz : dw;
    float inv = (deg > 0) ? 1.f / den : 0.f;

    floatx4 o0, o1;
    o0.x = bf2f((unsigned short)rv[0]) + acc8[0] * inv;
    o0.y = bf2f((unsigned short)rv[1]) + acc8[1] * inv;
    o0.z = bf2f((unsigned short)rv[2]) + acc8[2] * inv;
    o0.w = bf2f((unsigned short)rv[3]) + acc8[3] * inv;
    o1.x = bf2f((unsigned short)rv[4]) + acc8[4] * inv;
    o1.y = bf2f((unsigned short)rv[5]) + acc8[5] * inv;
    o1.z = bf2f((unsigned short)rv[6]) + acc8[6] * inv;
    o1.w = bf2f((unsigned short)rv[7]) + acc8[7] * inv;
    __builtin_nontemporal_store(o0, (floatx4*)&out[(size_t)n * C + t16 * 8]);
    __builtin_nontemporal_store(o1, (floatx4*)&out[(size_t)n * C + t16 * 8 + 4]);
}

// ---------------------------------------------------------------------------
extern "C" void kernel_launch(void* const* d_in, const int* in_sizes, int n_in,
                              void* d_out, int out_size, void* d_ws, size_t ws_size,
                              hipStream_t stream)
{
    const float* feat    = (const float*)d_in[0];
    const float* W       = (const float*)d_in[1];
    const float* att_src = (const float*)d_in[2];
    const float* att_dst = (const float*)d_in[3];
    const float* W_res   = (const float*)d_in[4];
    const int*   src     = (const int*)d_in[5];
    const int*   dst     = (const int*)d_in[6];
    float* out = (float*)d_out;

    char* p = (char*)d_ws;
    unsigned short* xb   = (unsigned short*)p; p += (size_t)NN * C * sizeof(unsigned short);
    unsigned short* resb = (unsigned short*)p; p += (size_t)NN * C * sizeof(unsigned short);
    unsigned short* Btf  = (unsigned short*)p; p += (size_t)256 * 128 * sizeof(unsigned short);
    float* a_s = (float*)p;            p += (size_t)NN * 4 * sizeof(float);
    float* a_d = (float*)p;            p += (size_t)NN * 4 * sizeof(float);
    int* row_ptr = (int*)p;            p += (size_t)(NN + 1) * sizeof(int);
    int* counts  = (int*)p;            p += (size_t)NBLK1 * 256 * sizeof(int);
    int* bucket_base = (int*)p;        p += (size_t)257 * sizeof(int);
    int* bpack   = (int*)p;            p += (size_t)NE * sizeof(int);
    int* csr_src = (int*)p;            p += (size_t)NE * sizeof(int);

    fat1_kernel<<<FAT1_NB, 256, 0, stream>>>(W, W_res, Btf, dst, counts);
    sortscan_kernel<<<1, 256, 0, stream>>>(counts, bucket_base);
    fat2_kernel<<<FAT2_NB, 256, 0, stream>>>(src, dst, counts, bucket_base, bpack,
                                             feat, Btf, att_src, att_dst,
                                             xb, resb, a_s, a_d);
    sort3_kernel<<<NBUCK, 512, 0, stream>>>(bpack, bucket_base, row_ptr, csr_src);
    agg_kernel<<<NN / 16, 256, 0, stream>>>(xb, resb, a_s, a_d, row_ptr, csr_src, out);
}